// Round 6
// baseline (75.183 us; speedup 1.0000x reference)
//
#include <hip/hip_runtime.h>
#include <hip/hip_bf16.h>

#define NROWS 8192
#define DDIM 128

typedef __attribute__((ext_vector_type(8))) short bf16x8;
typedef __attribute__((ext_vector_type(4))) float f32x4;

// ---------------------------------------------------------------------------
// prep: fp32 -> bf16 (RNE) in MFMA-FRAGMENT-PACKED layout + reciprocal norms.
// Packed layout: element (row, k) at byte offset
//   ((row>>4)*4 + (k>>5))*1024 + (row&15)*64 + ((k&31)>>3)*16 + (k&7)*2
// (each 16-row x 32-k MFMA fragment = one contiguous 1KB block).
// rn = 1/||x||  (norms ~8-16 -> eps path of max(n1*n2,1e-8) unreachable).
// ---------------------------------------------------------------------------
__global__ __launch_bounds__(256) void prep_kernel(
    const float* __restrict__ in1, const float* __restrict__ in2,
    __hip_bfloat16* __restrict__ Apk, __hip_bfloat16* __restrict__ Bpk,
    float* __restrict__ rn1, float* __restrict__ rn2) {
  int gw = (blockIdx.x * 256 + threadIdx.x) >> 6;   // global wave id
  int l = threadIdx.x & 63;
  int row;
  const float* src;
  char* dstbase;
  float* nrm;
  if (gw < NROWS) {
    row = gw;
    src = in1 + (size_t)row * DDIM;
    dstbase = (char*)Apk;
    nrm = rn1 + row;
  } else {
    row = gw - NROWS;
    src = in2 + (size_t)row * DDIM;
    dstbase = (char*)Bpk;
    nrm = rn2 + row;
  }
  float2 v = ((const float2*)src)[l];   // k = 2l, 2l+1
  float s = v.x * v.x + v.y * v.y;
  __hip_bfloat162 h;
  h.x = __float2bfloat16(v.x);
  h.y = __float2bfloat16(v.y);

  int rb = row >> 4, ri = row & 15;
  int sk = l >> 4;             // (2l)>>5
  int q2 = (l & 15) >> 2;      // ((2l)&31)>>3
  int j2 = l & 3;              // pair within 8-elem group
  char* dst = dstbase + (size_t)(rb * 4 + sk) * 1024 + ri * 64 + q2 * 16 + j2 * 4;
  *(__hip_bfloat162*)dst = h;

#pragma unroll
  for (int off = 1; off < 64; off <<= 1) s += __shfl_xor(s, off);
  if (l == 0) *nrm = 1.0f / sqrtf(s);
}

// ---------------------------------------------------------------------------
// cos_gemm: C[i][j] = dot(A_i, B_j) * rn1[i] * rn2[j]
// 64x128 tile/block, 4 blocks/CU (32KB LDS, ~90 VGPR), ONE barrier per block.
// Operand fragments: direct global->VGPR 1KB contiguous loads (packed layout),
// L2-resident via XCD-chunk swizzle (per-XCD set = 256KB A + 2MB B < 4MB L2).
// Output: repack through 32KB LDS, then NONTEMPORAL 512B-contiguous stores
// (write stream bypasses L2 so it never evicts the panels).
// High blocks/CU keeps some block in its store phase at all times ->
// near-continuous store stream (the R1-R5 limiter was store duty cycle).
// ---------------------------------------------------------------------------
__global__ __launch_bounds__(256, 4) void cos_gemm(
    const __hip_bfloat16* __restrict__ Apk, const __hip_bfloat16* __restrict__ Bpk,
    const float* __restrict__ rn1, const float* __restrict__ rn2,
    float* __restrict__ out) {
  __shared__ char lds[32 * 1024];

  const int tid = threadIdx.x;
  const int l = tid & 63;
  const int w = tid >> 6;             // wave 0..3
  const int q = l >> 4;               // 0..3
  const int c16 = l & 15;             // 0..15
  const int wr = w >> 1, wc = w & 1;  // 2x2 wave grid; wave owns 32x64 out

  // XCD-chunk swizzle: xcd = wg&7 owns 16 row-tiles x 64 col-tiles,
  // col fastest. Grid 8192 = 128 row-tiles(64) x 64 col-tiles(128).
  int wg = blockIdx.x;
  int xcd = wg & 7;
  int c = wg >> 3;                    // 0..1023
  const int brow = (xcd * 16 + (c >> 6)) * 64;
  const int bcol = (c & 63) * 128;

  const char* Ap = (const char*)Apk;
  const char* Bp = (const char*)Bpk;
  const int rb0a = (brow >> 4) + wr * 2;   // wave's A 16-row fragment blocks
  const int rb0b = (bcol >> 4) + wc * 4;   // wave's B 16-row fragment blocks
  const int laneoff = c16 * 64 + q * 16;

  // MFMA, operands swapped: lane holds 4 consecutive output COLUMNS.
  //   i = brow + wr*32 + m*16 + c16,  j = bcol + wc*64 + n*16 + q*4 + r
  f32x4 acc[2][4] = {};
#pragma unroll
  for (int s = 0; s < 4; ++s) {       // K steps of 32
    bf16x8 af[2], bfr[4];
#pragma unroll
    for (int m = 0; m < 2; ++m)
      af[m] = *(const bf16x8*)(Ap + (size_t)((rb0a + m) * 4 + s) * 1024 + laneoff);
#pragma unroll
    for (int n = 0; n < 4; ++n)
      bfr[n] = *(const bf16x8*)(Bp + (size_t)((rb0b + n) * 4 + s) * 1024 + laneoff);
#pragma unroll
    for (int m = 0; m < 2; ++m)
#pragma unroll
      for (int n = 0; n < 4; ++n)
        acc[m][n] =
            __builtin_amdgcn_mfma_f32_16x16x32_bf16(bfr[n], af[m], acc[m][n], 0, 0, 0);
  }

  // Scales
  float r1v[2];
#pragma unroll
  for (int m = 0; m < 2; ++m) r1v[m] = rn1[brow + wr * 32 + m * 16 + c16];
  float4 r2v[4];
#pragma unroll
  for (int n = 0; n < 4; ++n)
    r2v[n] = *(const float4*)&rn2[bcol + wc * 64 + n * 16 + q * 4];

  // Repack (scaled) into LDS: local row 0..63 (stride 512B), granule
  // g = col/4 XOR-swizzled by row for bank spread.
#pragma unroll
  for (int m = 0; m < 2; ++m) {
    int row = wr * 32 + m * 16 + c16;
#pragma unroll
    for (int n = 0; n < 4; ++n) {
      int g = wc * 16 + n * 4 + q;
      f32x4 v;
      v[0] = acc[m][n][0] * r1v[m] * r2v[n].x;
      v[1] = acc[m][n][1] * r1v[m] * r2v[n].y;
      v[2] = acc[m][n][2] * r1v[m] * r2v[n].z;
      v[3] = acc[m][n][3] * r1v[m] * r2v[n].w;
      *(f32x4*)(lds + (size_t)row * 512 + ((g ^ (row & 31)) * 16)) = v;
    }
  }
  __syncthreads();

  // Store: wave w -> local rows [w*16, w*16+16); each instr = 2 rows x 512B
  // contiguous (4 full 128B lines) -> nontemporal-safe, fill-kernel-like.
#pragma unroll
  for (int i = 0; i < 8; ++i) {
    int row = w * 16 + i * 2 + (l >> 5);
    int g = l & 31;
    f32x4 v = *(const f32x4*)(lds + (size_t)row * 512 + ((g ^ (row & 31)) * 16));
    __builtin_nontemporal_store(
        v, (f32x4*)(out + (size_t)(brow + row) * NROWS + bcol + g * 4));
  }
}

extern "C" void kernel_launch(void* const* d_in, const int* in_sizes, int n_in,
                              void* d_out, int out_size, void* d_ws, size_t ws_size,
                              hipStream_t stream) {
  const float* in1 = (const float*)d_in[0];
  const float* in2 = (const float*)d_in[1];
  float* out = (float*)d_out;
  char* ws = (char*)d_ws;

  __hip_bfloat16* Apk = (__hip_bfloat16*)(ws);                             // 2 MB packed
  __hip_bfloat16* Bpk = (__hip_bfloat16*)(ws + (size_t)NROWS * DDIM * 2);  // 2 MB packed
  float* rn1 = (float*)(ws + (size_t)NROWS * DDIM * 4);                    // 32 KB
  float* rn2 = (float*)(ws + (size_t)NROWS * DDIM * 4 + NROWS * 4);        // 32 KB

  // 16384 rows total (A + B), one wave per row, 4 waves per block
  prep_kernel<<<dim3(16384 / 4), 256, 0, stream>>>(in1, in2, Apk, Bpk, rn1, rn2);
  cos_gemm<<<dim3(8192), 256, 0, stream>>>(Apk, Bpk, rn1, rn2, out);
}